// Round 1
// baseline (220.681 us; speedup 1.0000x reference)
//
#include <hip/hip_runtime.h>

#define HH 128
#define WW 128
#define KK 64
#define SS 16
#define NSTEPS 64
#define VOLRADIUS 256.0f

__global__ __launch_bounds__(256) void raymarch_kernel(
    const float* __restrict__ viewpos,   // [3]   (already B=1)
    const float* __restrict__ raydir,    // [H,W,3]
    const float* __restrict__ tpl,       // [K,4,S,S,S]
    const float* __restrict__ primpos,   // [K,3]
    const float* __restrict__ primrot,   // [K,3,3]
    const float* __restrict__ primscale, // [K,3]
    const float* __restrict__ dtp,       // [1]
    float* __restrict__ out)             // rgba[4,H,W] | beg[H,W,3] | end[H,W,3]
{
    const int lane = threadIdx.x & 63;
    const int wid  = (int)((blockIdx.x * blockDim.x + threadIdx.x) >> 6);
    if (wid >= HH * WW) return;
    const int h = wid / WW, w = wid % WW;

    const float vx = viewpos[0] / VOLRADIUS;
    const float vy = viewpos[1] / VOLRADIUS;
    const float vz = viewpos[2] / VOLRADIUS;
    const float dtn = dtp[0] / VOLRADIUS;

    const float rx = raydir[(h * WW + w) * 3 + 0];
    const float ry = raydir[(h * WW + w) * 3 + 1];
    const float rz = raydir[(h * WW + w) * 3 + 2];

    // ray - AABB slab intersection with [-1,1]^3
    float t1x = (-1.f - vx) / rx, t2x = (1.f - vx) / rx;
    float t1y = (-1.f - vy) / ry, t2y = (1.f - vy) / ry;
    float t1z = (-1.f - vz) / rz, t2z = (1.f - vz) / rz;
    float tmin = fmaxf(fminf(t1x, t2x), fmaxf(fminf(t1y, t2y), fminf(t1z, t2z)));
    float tmax = fminf(fmaxf(t1x, t2x), fminf(fmaxf(t1y, t2y), fmaxf(t1z, t2z)));
    bool inter = tmin < tmax;
    float tmin_ = inter ? tmin : 0.f;
    float tmax_ = inter ? tmax : 0.f;
    float t0 = fmaxf(tmin_, 0.f);

    // this lane's primitive, held in registers for the whole march
    const float px = primpos[lane * 3 + 0];
    const float py = primpos[lane * 3 + 1];
    const float pz = primpos[lane * 3 + 2];
    // einsum 'bhwki,bkij->bhwkj': y_j = sum_i xm_i * R[i][j]  (R row-major [3][3])
    const float r00 = primrot[lane * 9 + 0], r01 = primrot[lane * 9 + 1], r02 = primrot[lane * 9 + 2];
    const float r10 = primrot[lane * 9 + 3], r11 = primrot[lane * 9 + 4], r12 = primrot[lane * 9 + 5];
    const float r20 = primrot[lane * 9 + 6], r21 = primrot[lane * 9 + 7], r22 = primrot[lane * 9 + 8];
    const float sx = primscale[lane * 3 + 0];
    const float sy = primscale[lane * 3 + 1];
    const float sz = primscale[lane * 3 + 2];
    const float* tp = tpl + (size_t)lane * 4 * SS * SS * SS;

    float accR = 0.f, accG = 0.f, accB = 0.f, accA = 0.f;

    for (int i = 0; i < NSTEPS; ++i) {
        float t = t0 + (float)i * dtn;
        if (!(t < tmax_)) break;          // wave-uniform; contrib would be exactly 0
        float posx = vx + rx * t;
        float posy = vy + ry * t;
        float posz = vz + rz * t;
        float xmx = posx - px, xmy = posy - py, xmz = posz - pz;
        float y0 = (xmx * r00 + xmy * r10 + xmz * r20) * sx;
        float y1 = (xmx * r01 + xmy * r11 + xmz * r21) * sy;
        float y2 = (xmx * r02 + xmy * r12 + xmz * r22) * sz;

        float sv0 = 0.f, sv1 = 0.f, sv2 = 0.f, sv3 = 0.f;
        if (fabsf(y0) < 1.f && fabsf(y1) < 1.f && fabsf(y2) < 1.f) {
            // align_corners trilinear sample; inside => g in (0, S-1), clip is a no-op
            float gx = (y0 + 1.f) * (0.5f * (SS - 1));
            float gy = (y1 + 1.f) * (0.5f * (SS - 1));
            float gz = (y2 + 1.f) * (0.5f * (SS - 1));
            float fgx = floorf(gx), fgy = floorf(gy), fgz = floorf(gz);
            int x0 = min(max((int)fgx, 0), SS - 2);
            int y0i = min(max((int)fgy, 0), SS - 2);
            int z0 = min(max((int)fgz, 0), SS - 2);
            float fx = gx - (float)x0;
            float fy = gy - (float)y0i;
            float fz = gz - (float)z0;
            int idx = z0 * (SS * SS) + y0i * SS + x0;
            float sv[4];
#pragma unroll
            for (int c = 0; c < 4; ++c) {
                const float* tc = tp + c * (SS * SS * SS);
                float c000 = tc[idx],                c001 = tc[idx + 1];
                float c010 = tc[idx + SS],           c011 = tc[idx + SS + 1];
                float c100 = tc[idx + SS * SS],      c101 = tc[idx + SS * SS + 1];
                float c110 = tc[idx + SS * SS + SS], c111 = tc[idx + SS * SS + SS + 1];
                float c00 = c000 * (1.f - fx) + c001 * fx;
                float c01 = c010 * (1.f - fx) + c011 * fx;
                float c10 = c100 * (1.f - fx) + c101 * fx;
                float c11 = c110 * (1.f - fx) + c111 * fx;
                sv[c] = (c00 * (1.f - fy) + c01 * fy) * (1.f - fz)
                      + (c10 * (1.f - fy) + c11 * fy) * fz;
            }
            sv0 = sv[0]; sv1 = sv[1]; sv2 = sv[2]; sv3 = sv[3];
        }

        // butterfly reduce over 64 lanes (fp add commutative -> identical in all lanes)
#pragma unroll
        for (int off = 32; off > 0; off >>= 1) {
            sv0 += __shfl_xor(sv0, off, 64);
            sv1 += __shfl_xor(sv1, off, 64);
            sv2 += __shfl_xor(sv2, off, 64);
            sv3 += __shfl_xor(sv3, off, 64);
        }

        // saturating additive compositing (valid==1 here since t < tmax_)
        float alpha = sv3 * dtn;
        float contrib = fminf(accA + alpha, 1.f) - accA;
        accR += sv0 * contrib;
        accG += sv1 * contrib;
        accB += sv2 * contrib;
        accA += contrib;
        if (accA >= 1.f) break;           // all further contribs are exactly 0
    }

    if (lane == 0) {
        const int pix = h * WW + w;
        out[0 * HH * WW + pix] = accR;
        out[1 * HH * WW + pix] = accG;
        out[2 * HH * WW + pix] = accB;
        out[3 * HH * WW + pix] = accA;
        const int base1 = 4 * HH * WW;
        out[base1 + pix * 3 + 0] = vx + rx * tmin_;
        out[base1 + pix * 3 + 1] = vy + ry * tmin_;
        out[base1 + pix * 3 + 2] = vz + rz * tmin_;
        const int base2 = base1 + HH * WW * 3;
        out[base2 + pix * 3 + 0] = vx + rx * tmax_;
        out[base2 + pix * 3 + 1] = vy + ry * tmax_;
        out[base2 + pix * 3 + 2] = vz + rz * tmax_;
    }
}

extern "C" void kernel_launch(void* const* d_in, const int* in_sizes, int n_in,
                              void* d_out, int out_size, void* d_ws, size_t ws_size,
                              hipStream_t stream) {
    const float* viewpos   = (const float*)d_in[0];
    // d_in[1] = viewrot, unused by the reference
    const float* raydir    = (const float*)d_in[2];
    const float* tpl       = (const float*)d_in[3];
    const float* primpos   = (const float*)d_in[4];
    const float* primrot   = (const float*)d_in[5];
    const float* primscale = (const float*)d_in[6];
    const float* dtp       = (const float*)d_in[7];
    float* out = (float*)d_out;

    dim3 grid(4096), block(256);
    hipLaunchKernelGGL(raymarch_kernel, grid, block, 0, stream,
                       viewpos, raydir, tpl, primpos, primrot, primscale, dtp, out);
}

// Round 2
// 46.699 us; speedup vs baseline: 4.7256x; 4.7256x over previous
//
#include <hip/hip_runtime.h>

#define HH 128
#define WW 128
#define KK 64
#define SS 16
#define NSTEPS 64
#define VOLRADIUS 256.0f
#define CULL_EPS 1e-3f

__global__ __launch_bounds__(256) void raymarch_kernel(
    const float* __restrict__ viewpos,   // [3]
    const float* __restrict__ raydir,    // [H,W,3]
    const float* __restrict__ tpl,       // [K,4,S,S,S]
    const float* __restrict__ primpos,   // [K,3]
    const float* __restrict__ primrot,   // [K,3,3]
    const float* __restrict__ primscale, // [K,3]
    const float* __restrict__ dtp,       // [1]
    float* __restrict__ out)             // rgba[4,H,W] | beg[H,W,3] | end[H,W,3]
{
    const int lane = threadIdx.x & 63;
    const int wid  = (int)((blockIdx.x * blockDim.x + threadIdx.x) >> 6);
    if (wid >= HH * WW) return;
    const int h = wid / WW, w = wid % WW;

    const float vx = viewpos[0] / VOLRADIUS;
    const float vy = viewpos[1] / VOLRADIUS;
    const float vz = viewpos[2] / VOLRADIUS;
    const float dtn = dtp[0] / VOLRADIUS;

    const float rx = raydir[(h * WW + w) * 3 + 0];
    const float ry = raydir[(h * WW + w) * 3 + 1];
    const float rz = raydir[(h * WW + w) * 3 + 2];

    // ray - AABB slab intersection with [-1,1]^3 (exactly as reference)
    float t1x = (-1.f - vx) / rx, t2x = (1.f - vx) / rx;
    float t1y = (-1.f - vy) / ry, t2y = (1.f - vy) / ry;
    float t1z = (-1.f - vz) / rz, t2z = (1.f - vz) / rz;
    float tmin = fmaxf(fminf(t1x, t2x), fmaxf(fminf(t1y, t2y), fminf(t1z, t2z)));
    float tmax = fminf(fmaxf(t1x, t2x), fminf(fmaxf(t1y, t2y), fmaxf(t1z, t2z)));
    bool inter = tmin < tmax;
    float tmin_ = inter ? tmin : 0.f;
    float tmax_ = inter ? tmax : 0.f;
    float t0 = fmaxf(tmin_, 0.f);

    // lane = step index i
    const float t = t0 + (float)lane * dtn;          // identical expression to ref
    const bool tvalid = t < tmax_;
    const float posx = vx + rx * t;
    const float posy = vy + ry * t;
    const float posz = vz + rz * t;

    // this lane's primitive (lane = prim index k for the culling phase)
    const float px = primpos[lane * 3 + 0];
    const float py = primpos[lane * 3 + 1];
    const float pz = primpos[lane * 3 + 2];
    const float r00 = primrot[lane * 9 + 0], r01 = primrot[lane * 9 + 1], r02 = primrot[lane * 9 + 2];
    const float r10 = primrot[lane * 9 + 3], r11 = primrot[lane * 9 + 4], r12 = primrot[lane * 9 + 5];
    const float r20 = primrot[lane * 9 + 6], r21 = primrot[lane * 9 + 7], r22 = primrot[lane * 9 + 8];
    const float sx = primscale[lane * 3 + 0];
    const float sy = primscale[lane * 3 + 1];
    const float sz = primscale[lane * 3 + 2];

    // conservative ray-vs-OBB cull in local y-space: y(t) ~= b + t*d, box widened by CULL_EPS
    {
        // (fall through; scope keeps temporaries from living long)
    }
    float bx = ((vx - px) * r00 + (vy - py) * r10 + (vz - pz) * r20) * sx;
    float by = ((vx - px) * r01 + (vy - py) * r11 + (vz - pz) * r21) * sy;
    float bz = ((vx - px) * r02 + (vy - py) * r12 + (vz - pz) * r22) * sz;
    float dxl = (rx * r00 + ry * r10 + rz * r20) * sx;
    float dyl = (rx * r01 + ry * r11 + rz * r21) * sy;
    float dzl = (rx * r02 + ry * r12 + rz * r22) * sz;

    float tend = fminf(tmax_, t0 + 63.f * dtn);
    float te = t0, txx = tend;
    {
        float b[3] = {bx, by, bz};
        float d[3] = {dxl, dyl, dzl};
#pragma unroll
        for (int j = 0; j < 3; ++j) {
            float ta, tb;
            if (fabsf(d[j]) > 1e-12f) {
                float inv = 1.f / d[j];
                ta = (-1.f - CULL_EPS - b[j]) * inv;
                tb = ( 1.f + CULL_EPS - b[j]) * inv;
            } else {
                bool ok = fabsf(b[j]) <= 1.f + CULL_EPS;
                ta = ok ? -3e38f : 3e38f;
                tb = ok ?  3e38f : -3e38f;
            }
            te  = fmaxf(te,  fminf(ta, tb));
            txx = fminf(txx, fmaxf(ta, tb));
        }
    }
    bool active = (te <= txx);
    unsigned long long mask = __ballot(active);

    float sv0 = 0.f, sv1 = 0.f, sv2 = 0.f, sv3 = 0.f;

    while (mask) {
        int k = __ffsll(mask) - 1;
        mask &= mask - 1;
        // broadcast prim k's params (bit-exact originals)
        float qpx = __shfl(px, k, 64), qpy = __shfl(py, k, 64), qpz = __shfl(pz, k, 64);
        float q00 = __shfl(r00, k, 64), q01 = __shfl(r01, k, 64), q02 = __shfl(r02, k, 64);
        float q10 = __shfl(r10, k, 64), q11 = __shfl(r11, k, 64), q12 = __shfl(r12, k, 64);
        float q20 = __shfl(r20, k, 64), q21 = __shfl(r21, k, 64), q22 = __shfl(r22, k, 64);
        float qsx = __shfl(sx, k, 64), qsy = __shfl(sy, k, 64), qsz = __shfl(sz, k, 64);

        // exact per-point transform (same expression as the validated round-1 kernel)
        float xmx = posx - qpx, xmy = posy - qpy, xmz = posz - qpz;
        float y0 = (xmx * q00 + xmy * q10 + xmz * q20) * qsx;
        float y1 = (xmx * q01 + xmy * q11 + xmz * q21) * qsy;
        float y2 = (xmx * q02 + xmy * q12 + xmz * q22) * qsz;

        bool samp = tvalid && fabsf(y0) < 1.f && fabsf(y1) < 1.f && fabsf(y2) < 1.f;
        if (__any(samp)) {
            if (samp) {
                const float* tp = tpl + (size_t)k * (4 * SS * SS * SS);
                float gx = (y0 + 1.f) * (0.5f * (SS - 1));
                float gy = (y1 + 1.f) * (0.5f * (SS - 1));
                float gz = (y2 + 1.f) * (0.5f * (SS - 1));
                float fgx = floorf(gx), fgy = floorf(gy), fgz = floorf(gz);
                int x0 = min(max((int)fgx, 0), SS - 2);
                int y0i = min(max((int)fgy, 0), SS - 2);
                int z0 = min(max((int)fgz, 0), SS - 2);
                float fx = gx - (float)x0;
                float fy = gy - (float)y0i;
                float fz = gz - (float)z0;
                int idx = z0 * (SS * SS) + y0i * SS + x0;
                float sv[4];
#pragma unroll
                for (int c = 0; c < 4; ++c) {
                    const float* tc = tp + c * (SS * SS * SS);
                    float c000 = tc[idx],                c001 = tc[idx + 1];
                    float c010 = tc[idx + SS],           c011 = tc[idx + SS + 1];
                    float c100 = tc[idx + SS * SS],      c101 = tc[idx + SS * SS + 1];
                    float c110 = tc[idx + SS * SS + SS], c111 = tc[idx + SS * SS + SS + 1];
                    float c00 = c000 * (1.f - fx) + c001 * fx;
                    float c01 = c010 * (1.f - fx) + c011 * fx;
                    float c10 = c100 * (1.f - fx) + c101 * fx;
                    float c11 = c110 * (1.f - fx) + c111 * fx;
                    sv[c] = (c00 * (1.f - fy) + c01 * fy) * (1.f - fz)
                          + (c10 * (1.f - fy) + c11 * fy) * fz;
                }
                sv0 += sv[0]; sv1 += sv[1]; sv2 += sv[2]; sv3 += sv[3];
            }
        }
    }

    // compositing in closed form: alpha >= 0 so accA_i = min(prefix_sum, 1)
    float alpha = tvalid ? sv3 * dtn : 0.f;
    float A = alpha;                                  // inclusive prefix over lanes
#pragma unroll
    for (int d = 1; d < 64; d <<= 1) {
        float u = __shfl_up(A, d, 64);
        if (lane >= d) A += u;
    }
    float Aex = __shfl_up(A, 1, 64);
    if (lane == 0) Aex = 0.f;
    float contrib = fminf(Aex + alpha, 1.f) - fminf(Aex, 1.f);

    float cr = sv0 * contrib, cg = sv1 * contrib, cb = sv2 * contrib;
#pragma unroll
    for (int off = 32; off > 0; off >>= 1) {
        cr += __shfl_xor(cr, off, 64);
        cg += __shfl_xor(cg, off, 64);
        cb += __shfl_xor(cb, off, 64);
    }
    float Atot = __shfl(A, 63, 64);
    float accA = fminf(Atot, 1.f);

    if (lane == 0) {
        const int pix = h * WW + w;
        out[0 * HH * WW + pix] = cr;
        out[1 * HH * WW + pix] = cg;
        out[2 * HH * WW + pix] = cb;
        out[3 * HH * WW + pix] = accA;
        const int base1 = 4 * HH * WW;
        out[base1 + pix * 3 + 0] = vx + rx * tmin_;
        out[base1 + pix * 3 + 1] = vy + ry * tmin_;
        out[base1 + pix * 3 + 2] = vz + rz * tmin_;
        const int base2 = base1 + HH * WW * 3;
        out[base2 + pix * 3 + 0] = vx + rx * tmax_;
        out[base2 + pix * 3 + 1] = vy + ry * tmax_;
        out[base2 + pix * 3 + 2] = vz + rz * tmax_;
    }
}

extern "C" void kernel_launch(void* const* d_in, const int* in_sizes, int n_in,
                              void* d_out, int out_size, void* d_ws, size_t ws_size,
                              hipStream_t stream) {
    const float* viewpos   = (const float*)d_in[0];
    // d_in[1] = viewrot, unused by the reference
    const float* raydir    = (const float*)d_in[2];
    const float* tpl       = (const float*)d_in[3];
    const float* primpos   = (const float*)d_in[4];
    const float* primrot   = (const float*)d_in[5];
    const float* primscale = (const float*)d_in[6];
    const float* dtp       = (const float*)d_in[7];
    float* out = (float*)d_out;

    dim3 grid(4096), block(256);
    hipLaunchKernelGGL(raymarch_kernel, grid, block, 0, stream,
                       viewpos, raydir, tpl, primpos, primrot, primscale, dtp, out);
}

// Round 3
// 42.842 us; speedup vs baseline: 5.1510x; 1.0900x over previous
//
#include <hip/hip_runtime.h>

#define HH 128
#define WW 128
#define KK 64
#define SS 16
#define S3 (SS * SS * SS)
#define VOLRADIUS 256.0f
#define CULL_EPS 1e-3f
#define GPIX 4

// ---- DPP inclusive scan (gfx9 pattern: row_shr 1/2/4/8 + row_bcast 15/31) ----
template <int CTRL, int RM>
__device__ __forceinline__ float dpp_add(float x) {
    int y = __builtin_amdgcn_update_dpp(0, __float_as_int(x), CTRL, RM, 0xF, false);
    return x + __int_as_float(y);
}
__device__ __forceinline__ float wave_incl_scan(float x) {
    x = dpp_add<0x111, 0xF>(x);   // row_shr:1
    x = dpp_add<0x112, 0xF>(x);   // row_shr:2
    x = dpp_add<0x114, 0xF>(x);   // row_shr:4
    x = dpp_add<0x118, 0xF>(x);   // row_shr:8
    x = dpp_add<0x142, 0xA>(x);   // row_bcast:15 -> rows 1,3
    x = dpp_add<0x143, 0xC>(x);   // row_bcast:31 -> rows 2,3
    return x;                     // lane i = sum(lanes 0..i); lane 63 = total
}

#define LERP4(a, b, f) make_float4(a.x*(1.f-(f)) + b.x*(f), a.y*(1.f-(f)) + b.y*(f), \
                                   a.z*(1.f-(f)) + b.z*(f), a.w*(1.f-(f)) + b.w*(f))

// template [K,4,S,S,S] -> ws [K,S,S,S,4] so each trilinear corner is one float4
__global__ __launch_bounds__(256) void transpose_tpl(const float* __restrict__ tpl,
                                                     float4* __restrict__ tw) {
    int i = blockIdx.x * blockDim.x + threadIdx.x;      // 0 .. K*S3
    if (i >= KK * S3) return;
    int k = i >> 12, v = i & (S3 - 1);
    const float* src = tpl + ((size_t)k * 4 * S3) + v;
    tw[i] = make_float4(src[0], src[S3], src[2 * S3], src[3 * S3]);
}

template <bool TR>
__global__ __launch_bounds__(256) void raymarch_kernel(
    const float* __restrict__ viewpos,   // [3]
    const float* __restrict__ raydir,    // [H,W,3]
    const float* __restrict__ tpl,       // [K,4,S,S,S]
    const float* __restrict__ primpos,   // [K,3]
    const float* __restrict__ primrot,   // [K,3,3]
    const float* __restrict__ primscale, // [K,3]
    const float* __restrict__ dtp,       // [1]
    const float4* __restrict__ tw,       // [K,S3] rgba (if TR)
    float* __restrict__ out)
{
    const int lane = threadIdx.x & 63;
    const int wid  = (int)((blockIdx.x * blockDim.x + threadIdx.x) >> 6);
    if (wid >= (HH * WW) / GPIX) return;
    const int pix0 = wid * GPIX;                 // 4 adjacent pixels in one row

    const float vx = viewpos[0] / VOLRADIUS;
    const float vy = viewpos[1] / VOLRADIUS;
    const float vz = viewpos[2] / VOLRADIUS;
    const float dtn = dtp[0] / VOLRADIUS;

    // lane = prim k: params for the cull phase
    const float px = primpos[lane*3+0], py = primpos[lane*3+1], pz = primpos[lane*3+2];
    const float r00 = primrot[lane*9+0], r01 = primrot[lane*9+1], r02 = primrot[lane*9+2];
    const float r10 = primrot[lane*9+3], r11 = primrot[lane*9+4], r12 = primrot[lane*9+5];
    const float r20 = primrot[lane*9+6], r21 = primrot[lane*9+7], r22 = primrot[lane*9+8];
    const float sx = primscale[lane*3+0], sy = primscale[lane*3+1], sz = primscale[lane*3+2];
    // origin in local prim space (ray-independent)
    const float bx = ((vx-px)*r00 + (vy-py)*r10 + (vz-pz)*r20) * sx;
    const float by = ((vx-px)*r01 + (vy-py)*r11 + (vz-pz)*r21) * sy;
    const float bz = ((vx-px)*r02 + (vy-py)*r12 + (vz-pz)*r22) * sz;

    float rx[GPIX], ry[GPIX], rz[GPIX], tmn[GPIX], tmx[GPIX];
    float posx[GPIX], posy[GPIX], posz[GPIX];
    bool tvalid[GPIX];
    unsigned long long mask = 0ull;

#pragma unroll
    for (int p = 0; p < GPIX; ++p) {
        const int pix = pix0 + p;
        const float Rx = raydir[pix*3+0], Ry = raydir[pix*3+1], Rz = raydir[pix*3+2];
        rx[p] = Rx; ry[p] = Ry; rz[p] = Rz;
        // slab vs [-1,1]^3, exactly as reference
        float t1x = (-1.f-vx)/Rx, t2x = (1.f-vx)/Rx;
        float t1y = (-1.f-vy)/Ry, t2y = (1.f-vy)/Ry;
        float t1z = (-1.f-vz)/Rz, t2z = (1.f-vz)/Rz;
        float tmin = fmaxf(fminf(t1x,t2x), fmaxf(fminf(t1y,t2y), fminf(t1z,t2z)));
        float tmax = fminf(fmaxf(t1x,t2x), fminf(fmaxf(t1y,t2y), fmaxf(t1z,t2z)));
        bool inter = tmin < tmax;
        float tmin_ = inter ? tmin : 0.f;
        float tmax_ = inter ? tmax : 0.f;
        tmn[p] = tmin_; tmx[p] = tmax_;
        float t0 = fmaxf(tmin_, 0.f);
        float t = t0 + (float)lane * dtn;          // lane = step index
        tvalid[p] = t < tmax_;
        posx[p] = vx + Rx*t; posy[p] = vy + Ry*t; posz[p] = vz + Rz*t;

        // conservative ray-vs-OBB cull in local space (widened by CULL_EPS)
        float dxl = (Rx*r00 + Ry*r10 + Rz*r20) * sx;
        float dyl = (Rx*r01 + Ry*r11 + Rz*r21) * sy;
        float dzl = (Rx*r02 + Ry*r12 + Rz*r22) * sz;
        float tend = fminf(tmax_, t0 + 63.f*dtn);
        float te = t0, tx = tend;
        float bb[3] = {bx, by, bz};
        float dd[3] = {dxl, dyl, dzl};
#pragma unroll
        for (int j = 0; j < 3; ++j) {
            float ta, tb2;
            if (fabsf(dd[j]) > 1e-12f) {
                float inv = 1.f / dd[j];
                ta  = (-1.f - CULL_EPS - bb[j]) * inv;
                tb2 = ( 1.f + CULL_EPS - bb[j]) * inv;
            } else {
                bool ok = fabsf(bb[j]) <= 1.f + CULL_EPS;
                ta  = ok ? -3e38f :  3e38f;
                tb2 = ok ?  3e38f : -3e38f;
            }
            te = fmaxf(te, fminf(ta, tb2));
            tx = fminf(tx, fmaxf(ta, tb2));
        }
        mask |= __ballot(te <= tx);
    }

    float sv0[GPIX] = {}, sv1[GPIX] = {}, sv2[GPIX] = {}, sv3[GPIX] = {};

    while (mask) {
        int k = __ffsll(mask) - 1;
        mask &= mask - 1;
        k = __builtin_amdgcn_readfirstlane(k);     // wave-uniform -> scalar loads
        const float qpx = primpos[k*3+0], qpy = primpos[k*3+1], qpz = primpos[k*3+2];
        const float q00 = primrot[k*9+0], q01 = primrot[k*9+1], q02 = primrot[k*9+2];
        const float q10 = primrot[k*9+3], q11 = primrot[k*9+4], q12 = primrot[k*9+5];
        const float q20 = primrot[k*9+6], q21 = primrot[k*9+7], q22 = primrot[k*9+8];
        const float qsx = primscale[k*3+0], qsy = primscale[k*3+1], qsz = primscale[k*3+2];

#pragma unroll
        for (int p = 0; p < GPIX; ++p) {
            float xmx = posx[p]-qpx, xmy = posy[p]-qpy, xmz = posz[p]-qpz;
            float y0 = (xmx*q00 + xmy*q10 + xmz*q20) * qsx;
            float y1 = (xmx*q01 + xmy*q11 + xmz*q21) * qsy;
            float y2 = (xmx*q02 + xmy*q12 + xmz*q22) * qsz;
            bool samp = tvalid[p] && fabsf(y0) < 1.f && fabsf(y1) < 1.f && fabsf(y2) < 1.f;
            if (samp) {
                float gx = (y0+1.f)*(0.5f*(SS-1));
                float gy = (y1+1.f)*(0.5f*(SS-1));
                float gz = (y2+1.f)*(0.5f*(SS-1));
                int x0  = min(max((int)floorf(gx), 0), SS-2);
                int y0i = min(max((int)floorf(gy), 0), SS-2);
                int z0  = min(max((int)floorf(gz), 0), SS-2);
                float fx = gx-(float)x0, fy = gy-(float)y0i, fz = gz-(float)z0;
                int idx = z0*(SS*SS) + y0i*SS + x0;
                if (TR) {
                    const float4* tb = tw + ((size_t)k << 12);
                    float4 c000 = tb[idx],            c001 = tb[idx+1];
                    float4 c010 = tb[idx+SS],         c011 = tb[idx+SS+1];
                    float4 c100 = tb[idx+SS*SS],      c101 = tb[idx+SS*SS+1];
                    float4 c110 = tb[idx+SS*SS+SS],   c111 = tb[idx+SS*SS+SS+1];
                    float4 c00 = LERP4(c000, c001, fx);
                    float4 c01 = LERP4(c010, c011, fx);
                    float4 c10 = LERP4(c100, c101, fx);
                    float4 c11 = LERP4(c110, c111, fx);
                    float4 e0 = LERP4(c00, c01, fy);
                    float4 e1 = LERP4(c10, c11, fy);
                    sv0[p] += e0.x*(1.f-fz) + e1.x*fz;
                    sv1[p] += e0.y*(1.f-fz) + e1.y*fz;
                    sv2[p] += e0.z*(1.f-fz) + e1.z*fz;
                    sv3[p] += e0.w*(1.f-fz) + e1.w*fz;
                } else {
                    const float* tp = tpl + (size_t)k * (4 * S3);
                    float sv[4];
#pragma unroll
                    for (int c = 0; c < 4; ++c) {
                        const float* tc = tp + c * S3;
                        float c000 = tc[idx],              c001 = tc[idx+1];
                        float c010 = tc[idx+SS],           c011 = tc[idx+SS+1];
                        float c100 = tc[idx+SS*SS],        c101 = tc[idx+SS*SS+1];
                        float c110 = tc[idx+SS*SS+SS],     c111 = tc[idx+SS*SS+SS+1];
                        float c00 = c000*(1.f-fx) + c001*fx;
                        float c01 = c010*(1.f-fx) + c011*fx;
                        float c10 = c100*(1.f-fx) + c101*fx;
                        float c11 = c110*(1.f-fx) + c111*fx;
                        sv[c] = (c00*(1.f-fy) + c01*fy)*(1.f-fz)
                              + (c10*(1.f-fy) + c11*fy)*fz;
                    }
                    sv0[p] += sv[0]; sv1[p] += sv[1]; sv2[p] += sv[2]; sv3[p] += sv[3];
                }
            }
        }
    }

#pragma unroll
    for (int p = 0; p < GPIX; ++p) {
        float alpha = tvalid[p] ? sv3[p] * dtn : 0.f;
        float A = wave_incl_scan(alpha);               // inclusive prefix of alpha
        float Aex = __shfl_up(A, 1, 64);
        if (lane == 0) Aex = 0.f;
        // alpha>=0 => accA=min(prefix,1); contrib identical to reference recurrence
        float contrib = fminf(Aex + alpha, 1.f) - fminf(Aex, 1.f);
        float cr = wave_incl_scan(sv0[p] * contrib);   // lane63 = total
        float cg = wave_incl_scan(sv1[p] * contrib);
        float cb = wave_incl_scan(sv2[p] * contrib);
        float At = fminf(A, 1.f);
        if (lane == 63) {
            const int pix = pix0 + p;
            out[0*HH*WW + pix] = cr;
            out[1*HH*WW + pix] = cg;
            out[2*HH*WW + pix] = cb;
            out[3*HH*WW + pix] = At;
            const int b1 = 4*HH*WW;
            out[b1 + pix*3+0] = vx + rx[p]*tmn[p];
            out[b1 + pix*3+1] = vy + ry[p]*tmn[p];
            out[b1 + pix*3+2] = vz + rz[p]*tmn[p];
            const int b2 = b1 + HH*WW*3;
            out[b2 + pix*3+0] = vx + rx[p]*tmx[p];
            out[b2 + pix*3+1] = vy + ry[p]*tmx[p];
            out[b2 + pix*3+2] = vz + rz[p]*tmx[p];
        }
    }
}

extern "C" void kernel_launch(void* const* d_in, const int* in_sizes, int n_in,
                              void* d_out, int out_size, void* d_ws, size_t ws_size,
                              hipStream_t stream) {
    const float* viewpos   = (const float*)d_in[0];
    // d_in[1] = viewrot, unused by the reference
    const float* raydir    = (const float*)d_in[2];
    const float* tpl       = (const float*)d_in[3];
    const float* primpos   = (const float*)d_in[4];
    const float* primrot   = (const float*)d_in[5];
    const float* primscale = (const float*)d_in[6];
    const float* dtp       = (const float*)d_in[7];
    float* out = (float*)d_out;

    const size_t twbytes = (size_t)KK * S3 * 4 * sizeof(float);  // 4 MiB
    const int nwaves = (HH * WW) / GPIX;                          // 4096
    dim3 block(256), grid(nwaves * 64 / 256);                     // 1024 blocks

    if (ws_size >= twbytes) {
        transpose_tpl<<<dim3((KK * S3 + 255) / 256), block, 0, stream>>>(tpl, (float4*)d_ws);
        raymarch_kernel<true><<<grid, block, 0, stream>>>(
            viewpos, raydir, tpl, primpos, primrot, primscale, dtp,
            (const float4*)d_ws, out);
    } else {
        raymarch_kernel<false><<<grid, block, 0, stream>>>(
            viewpos, raydir, tpl, primpos, primrot, primscale, dtp,
            (const float4*)d_ws, out);
    }
}